// Round 18
// baseline (92.698 us; speedup 1.0000x reference)
//
#include <hip/hip_runtime.h>
#include <hip/hip_fp16.h>
#include <stdint.h>

#define B_ 4
#define C_ 128
#define H_ 128
#define W_ 128
#define HW 16384

typedef _Float16 h8 __attribute__((ext_vector_type(8)));
typedef float f32x16 __attribute__((ext_vector_type(16)));

__device__ __forceinline__ unsigned cvtpk_f16(float lo, float hi) {
    auto r = __builtin_amdgcn_cvt_pkrtz(lo, hi);
    return *(unsigned*)&r;
}

__device__ __forceinline__ unsigned blend_h2(unsigned c0, unsigned c1, unsigned c2, unsigned c3,
                                             __half2 G0, __half2 G1, __half2 G2, __half2 G3) {
    __half2 s = __hmul2(G0, *(__half2*)&c0);
    s = __hfma2(G1, *(__half2*)&c1, s);
    s = __hfma2(G2, *(__half2*)&c2, s);
    s = __hfma2(G3, *(__half2*)&c3, s);
    return *(unsigned*)&s;
}

__device__ __forceinline__ void gll16(const void* g, void* l) {
    __builtin_amdgcn_global_load_lds((const unsigned int*)g, (unsigned int*)l, 16, 0, 0);
}

// producer barrier: drain LDS writes only; global loads stay in flight
#define PBAR() do { \
    asm volatile("s_waitcnt lgkmcnt(0)" ::: "memory"); \
    __builtin_amdgcn_s_barrier(); \
    asm volatile("" ::: "memory"); \
} while (0)
// consumer barrier: no drain
#define CBAR() do { \
    asm volatile("" ::: "memory"); \
    __builtin_amdgcn_s_barrier(); \
    asm volatile("" ::: "memory"); \
} while (0)

// ---------------- fused prep: nhwc transpose + w1/w2 frag pack + border zero + BN fold ----------------
__global__ __launch_bounds__(256) void prep_all(const float* __restrict__ x,
                                                unsigned short* __restrict__ xh,
                                                const float* __restrict__ w1,
                                                const float* __restrict__ w2,
                                                unsigned short* __restrict__ w1f,
                                                unsigned short* __restrict__ w2f,
                                                unsigned short* __restrict__ o1p,
                                                const float* g1, const float* b1, const float* m1, const float* v1,
                                                const float* g2, const float* b2, const float* m2, const float* v2,
                                                float* inv1, float* sh1, float* inv2, float* sh2) {
    __shared__ unsigned short tile[32][36];
    int blk = blockIdx.x;
    int tid = threadIdx.x;
    if (blk >= 1282) {
        int nb = blk - 1282;
        int wt = nb & 3, ct = (nb >> 2) & 3, h = (nb >> 4) & 127, b = nb >> 11;
        int c = tid >> 3, seg = tid & 7;
        const float* srcp = x + ((size_t)((b * 128 + ct * 32 + c) * 128 + h) * 128) + wt * 32 + seg * 4;
        float4 v = *(const float4*)srcp;
        uint2 pk;
        pk.x = cvtpk_f16(v.x, v.y);
        pk.y = cvtpk_f16(v.z, v.w);
        *(uint2*)&tile[c][seg * 4] = pk;
        __syncthreads();
        int w = tid >> 3, s2 = tid & 7;
        unsigned a0 = tile[s2 * 4 + 0][w];
        unsigned a1 = tile[s2 * 4 + 1][w];
        unsigned a2 = tile[s2 * 4 + 2][w];
        unsigned a3 = tile[s2 * 4 + 3][w];
        uint2 o;
        o.x = (a1 << 16) | a0;
        o.y = (a3 << 16) | a2;
        *(uint2*)(xh + ((size_t)((b * 128 + h) * 128 + wt * 32 + w) * 128) + ct * 32 + s2 * 4) = o;
        return;
    }
    if (blk < 1152) {
        int i = blk * 256 + tid;
        const float* src = w1;
        unsigned short* dst = w1f;
        int j = i;
        if (i >= 147456) { j = i - 147456; src = w2; dst = w2f; }
        int o = j / 1152, rem = j % 1152;
        int c = rem / 9, tap = rem % 9;
        _Float16 hv = (_Float16)src[j];
        int s = o >> 5;
        int ks = c >> 4;
        int l = (o & 31) | (((c >> 3) & 1) << 5);
        int jj = c & 7;
        dst[(((tap * 4 + s) * 8 + ks) * 64 + l) * 8 + jj] = *(unsigned short*)&hv;
    } else if (blk < 1281) {
        int i = (blk - 1152) * 256 + tid;
        if (i < 33024) {
            int chunk = i & 15;
            int pos = i >> 4;
            int b = pos / 516;
            int r = pos % 516;
            int row, col;
            if (r < 130)      { row = 0;   col = r; }
            else if (r < 260) { row = 129; col = r - 130; }
            else { int j = r - 260; row = 1 + (j >> 1); col = (j & 1) * 129; }
            uint4 z = {0u, 0u, 0u, 0u};
            *(uint4*)((char*)o1p + (size_t)((b * 130 + row) * 130 + col) * 256 + chunk * 16) = z;
        }
    } else {
        if (tid < 128) {
            float iv = g1[tid] * rsqrtf(v1[tid] + 1e-5f);
            inv1[tid] = iv; sh1[tid] = b1[tid] - m1[tid] * iv;
        } else {
            int u = tid - 128;
            float iv = g2[u] * rsqrtf(v2[u] + 1e-5f);
            inv2[u] = iv; sh2[u] = b2[u] - m2[u] * iv;
        }
    }
}

// ---------------- GEMM1: producer/consumer, fp16, 2-deep producer pipeline, coalesced epilogue ----------------
__global__ __launch_bounds__(512, 4) void gemm1_k(
    const unsigned short* __restrict__ xh,
    const float* __restrict__ off,
    const unsigned short* __restrict__ w1f,
    const float* __restrict__ inv1,
    const float* __restrict__ sh1,
    unsigned short* __restrict__ out1p) {
    __shared__ __align__(16) char ldsv[2][16384];   // [64 p][16 chunks], 4-bit-XOR swz

    int bid = blockIdx.x;
    int swz = ((bid & 7) << 7) | (bid >> 3);
    int half = swz & 1, h = (swz >> 1) & 127, b = swz >> 8;
    int w0 = half * 64;
    int tid = threadIdx.x;
    int bH = b * H_;
    const char* xb8 = (const char*)xh;

    if (tid < 256) {
        // ================= PRODUCER =================
        int prow = tid >> 4;
        int seg = tid & 15;
        int sb = seg * 16;

        float dy[2][4], dx[2][4];
        float g[2][4][4];
        unsigned PX[4][4];
        uint4 buf[4][4];

#define OFFLOAD(TT) do { \
    int dyB_ = ((b * 18 + 2 * (TT)) * H_ + h) * W_ + w0; \
    _Pragma("unroll") \
    for (int c_ = 0; c_ < 4; ++c_) { \
        int p_ = prow + c_ * 16; \
        dy[(TT) & 1][c_] = off[dyB_ + p_]; \
        dx[(TT) & 1][c_] = off[dyB_ + HW + p_]; \
    } \
} while (0)

#define COORD(TT) do { \
    int kh_ = (TT) / 3 - 1, kw_ = (TT) % 3 - 1; \
    _Pragma("unroll") \
    for (int c_ = 0; c_ < 4; ++c_) { \
        int p_ = prow + c_ * 16; \
        float py_ = (float)(h + kh_) + dy[(TT) & 1][c_]; \
        float px_ = (float)(w0 + p_ + kw_) + dx[(TT) & 1][c_]; \
        float y0f_ = floorf(py_), x0f_ = floorf(px_); \
        int y0_ = (int)y0f_, x0_ = (int)x0f_; \
        float wy1_ = py_ - y0f_, wx1_ = px_ - x0f_; \
        float wy0_ = 1.f - wy1_, wx0_ = 1.f - wx1_; \
        int y1_ = y0_ + 1, x1_ = x0_ + 1; \
        g[(TT) & 1][c_][0] = ((unsigned)y0_ < 128u && (unsigned)x0_ < 128u) ? wy0_ * wx0_ : 0.f; \
        g[(TT) & 1][c_][1] = ((unsigned)y0_ < 128u && (unsigned)x1_ < 128u) ? wy0_ * wx1_ : 0.f; \
        g[(TT) & 1][c_][2] = ((unsigned)y1_ < 128u && (unsigned)x0_ < 128u) ? wy1_ * wx0_ : 0.f; \
        g[(TT) & 1][c_][3] = ((unsigned)y1_ < 128u && (unsigned)x1_ < 128u) ? wy1_ * wx1_ : 0.f; \
        int y0c_ = min(max(y0_, 0), 127), y1c_ = min(max(y1_, 0), 127); \
        int x0c_ = min(max(x0_, 0), 127), x1c_ = min(max(x1_, 0), 127); \
        int r0_ = (bH + y0c_) * W_, r1_ = (bH + y1c_) * W_; \
        PX[c_][0] = (unsigned)((r0_ + x0c_) * 256) + sb; \
        PX[c_][1] = (unsigned)((r0_ + x1c_) * 256) + sb; \
        PX[c_][2] = (unsigned)((r1_ + x0c_) * 256) + sb; \
        PX[c_][3] = (unsigned)((r1_ + x1c_) * 256) + sb; \
    } \
} while (0)

#define ISSUE_ALL() do { \
    _Pragma("unroll") \
    for (int c_ = 0; c_ < 4; ++c_) \
        _Pragma("unroll") \
        for (int k_ = 0; k_ < 4; ++k_) buf[c_][k_] = *(const uint4*)(xb8 + PX[c_][k_]); \
} while (0)

#define BLEND_ALL(TT) do { \
    char* vdst_ = &ldsv[(TT) & 1][0]; \
    _Pragma("unroll") \
    for (int c_ = 0; c_ < 4; ++c_) { \
        __half2 G0_ = __float2half2_rn(g[(TT) & 1][c_][0]); \
        __half2 G1_ = __float2half2_rn(g[(TT) & 1][c_][1]); \
        __half2 G2_ = __float2half2_rn(g[(TT) & 1][c_][2]); \
        __half2 G3_ = __float2half2_rn(g[(TT) & 1][c_][3]); \
        uint4 st_; \
        st_.x = blend_h2(buf[c_][0].x, buf[c_][1].x, buf[c_][2].x, buf[c_][3].x, G0_, G1_, G2_, G3_); \
        st_.y = blend_h2(buf[c_][0].y, buf[c_][1].y, buf[c_][2].y, buf[c_][3].y, G0_, G1_, G2_, G3_); \
        st_.z = blend_h2(buf[c_][0].z, buf[c_][1].z, buf[c_][2].z, buf[c_][3].z, G0_, G1_, G2_, G3_); \
        st_.w = blend_h2(buf[c_][0].w, buf[c_][1].w, buf[c_][2].w, buf[c_][3].w, G0_, G1_, G2_, G3_); \
        int row_ = prow + c_ * 16; \
        *(uint4*)(vdst_ + row_ * 256 + ((seg ^ (row_ & 15)) << 4)) = st_; \
    } \
} while (0)

        OFFLOAD(0);
        COORD(0);
        ISSUE_ALL();
        OFFLOAD(1);
        BLEND_ALL(0);
        COORD(1);
        ISSUE_ALL();
        OFFLOAD(2);
        PBAR();

        #pragma unroll
        for (int t = 0; t < 9; ++t) {
            if (t < 8) BLEND_ALL(t + 1);
            if (t < 7) { COORD(t + 2); ISSUE_ALL(); }
            if (t + 3 <= 8) OFFLOAD(t + 3);
            PBAR();
        }
#undef OFFLOAD
#undef COORD
#undef ISSUE_ALL
#undef BLEND_ALL
        CBAR();   // consumers finish writing epilogue tile into ldsv[0]
    } else {
        // ================= CONSUMER =================
        int ctid = tid - 256;
        int lane = ctid & 63, wq = ctid >> 6;
        int lp = lane & 31, hi = lane >> 5;
        int lsw = lp & 15;
        int bRow0 = lp * 256;
        int bRow1 = (32 + lp) * 256;

        f32x16 acc0 = {};
        f32x16 acc1 = {};
        h8 wreg[2][8];

        {
            const unsigned short* wb = w1f + wq * 4096 + lane * 8;
            #pragma unroll
            for (int ks = 0; ks < 8; ++ks) wreg[0][ks] = *(const h8*)(wb + ks * 512);
        }
        CBAR();
        #pragma unroll
        for (int t = 0; t < 9; ++t) {
            if (t < 8) {
                const unsigned short* wb = w1f + ((t + 1) * 4 + wq) * 4096 + lane * 8;
                #pragma unroll
                for (int ks = 0; ks < 8; ++ks) wreg[(t + 1) & 1][ks] = *(const h8*)(wb + ks * 512);
            }
            const char* vcur = &ldsv[t & 1][0];
            #pragma unroll
            for (int ks = 0; ks < 8; ++ks) {
                int q0 = 2 * ks + hi;
                int sl = (q0 ^ lsw) << 4;
                h8 b0 = *(const h8*)(vcur + bRow0 + sl);
                h8 b1 = *(const h8*)(vcur + bRow1 + sl);
                h8 a = wreg[t & 1][ks];
                acc0 = __builtin_amdgcn_mfma_f32_32x32x16_f16(a, b0, acc0, 0, 0, 0);
                acc1 = __builtin_amdgcn_mfma_f32_32x32x16_f16(a, b1, acc1, 0, 0, 0);
            }
            CBAR();
        }

        // epilogue: BN1 + ReLU -> fp16 -> swizzled LDS tile [64 p][128 o]
        char* eb = &ldsv[0][0];
        #pragma unroll
        for (int j = 0; j < 2; ++j) {
            int row = j * 32 + lp;
            #pragma unroll
            for (int k = 0; k < 4; ++k) {
                int o0 = wq * 32 + k * 8 + hi * 4;
                float4 iv = *(const float4*)(inv1 + o0);
                float4 sv = *(const float4*)(sh1 + o0);
                float e0, e1, e2, e3;
                if (j == 0) {
                    e0 = acc0[4 * k + 0]; e1 = acc0[4 * k + 1];
                    e2 = acc0[4 * k + 2]; e3 = acc0[4 * k + 3];
                } else {
                    e0 = acc1[4 * k + 0]; e1 = acc1[4 * k + 1];
                    e2 = acc1[4 * k + 2]; e3 = acc1[4 * k + 3];
                }
                float v0 = fmaxf(fmaf(e0, iv.x, sv.x), 0.f);
                float v1 = fmaxf(fmaf(e1, iv.y, sv.y), 0.f);
                float v2 = fmaxf(fmaf(e2, iv.z, sv.z), 0.f);
                float v3 = fmaxf(fmaf(e3, iv.w, sv.w), 0.f);
                uint2 pk2;
                pk2.x = cvtpk_f16(v0, v1);
                pk2.y = cvtpk_f16(v2, v3);
                int q = wq * 4 + k;   // 16B chunk index of o0
                *(uint2*)(eb + row * 256 + ((q ^ (row & 15)) << 4) + hi * 8) = pk2;
            }
        }
        PBAR();   // drain ds_writes, sync with producers
    }

    // ---- cooperative coalesced halo store (all 512 threads) ----
    {
        const char* eb = &ldsv[0][0];
        char* dstg = (char*)out1p + ((size_t)((b * 130 + h + 1) * 130 + 1 + w0)) * 256;
        #pragma unroll
        for (int it = 0; it < 2; ++it) {
            int ci = it * 512 + tid;
            int row = ci >> 4, q = ci & 15;
            uint4 v = *(const uint4*)(eb + row * 256 + ((q ^ (row & 15)) << 4));
            *(uint4*)(dstg + ci * 16) = v;
        }
    }
}

// ---------------- GEMM2: dense 3x3 conv, weights direct-from-global + reg dbuf, T14 reg-staged rows ----------------
__global__ __launch_bounds__(512, 4) void gemm2_k(
    const unsigned short* __restrict__ out1p,
    const unsigned short* __restrict__ w2f,
    const unsigned short* __restrict__ xh,
    const float* __restrict__ inv2,
    const float* __restrict__ sh2,
    float* __restrict__ outp) {
    __shared__ __align__(16) char ldsS[33280];   // input rows [130][16 chunks] swizzled

    int bid = blockIdx.x;
    int swz = ((bid & 7) << 6) | (bid >> 3);
    int h = swz & 127, b = swz >> 7;
    int tid = threadIdx.x, lane = tid & 63, wv = tid >> 6;
    int wq = wv >> 1, wp = wv & 1;
    int lp = lane & 31, hi = lane >> 5;

    f32x16 acc0 = {};
    f32x16 acc1 = {};
    h8 wreg[2][8];
    uint4 stg[4];
    uint4 stg4;

    // preload tap-0 weight slab
    {
        const unsigned short* wb = w2f + wq * 4096 + lane * 8;
        #pragma unroll
        for (int ks = 0; ks < 8; ++ks) wreg[0][ks] = *(const h8*)(wb + ks * 512);
    }

    // initial staging of kh=0 rows via global_load_lds (inverse-swizzled source)
    {
        const char* srow = (const char*)out1p + (size_t)((b * 130 + h) * 130) * 256;
        #pragma unroll
        for (int it = 0; it < 5; ++it) {
            int ci = it * 512 + tid;
            if (ci < 2080) {
                int r = ci >> 4, q = ci & 15;
                gll16(srow + r * 256 + ((q ^ (r & 15)) << 4), ldsS + ci * 16);
            }
        }
        __syncthreads();   // drains vmcnt (weights + stage)
    }

    #pragma unroll
    for (int t = 0; t < 9; ++t) {
        int kh = t / 3, kw = t % 3;
        // issue next-kh row loads into registers during the middle kw phase
        if (kw == 1 && kh < 2) {
            const char* srow = (const char*)out1p + (size_t)((b * 130 + h + kh + 1) * 130) * 256;
            #pragma unroll
            for (int it = 0; it < 4; ++it)
                stg[it] = *(const uint4*)(srow + (it * 512 + tid) * 16);
            if (tid < 32) stg4 = *(const uint4*)(srow + (2048 + tid) * 16);
        }
        if (t < 8) {
            const unsigned short* wb = w2f + ((t + 1) * 4 + wq) * 4096 + lane * 8;
            #pragma unroll
            for (int ks = 0; ks < 8; ++ks) wreg[(t + 1) & 1][ks] = *(const h8*)(wb + ks * 512);
        }
        #pragma unroll
        for (int ks = 0; ks < 8; ++ks) {
            int q0 = 2 * ks + hi;
            int pr0 = wp * 64 + lp + kw;
            int pr1 = pr0 + 32;
            h8 b0 = *(const h8*)(ldsS + pr0 * 256 + ((q0 ^ (pr0 & 15)) << 4));
            h8 b1 = *(const h8*)(ldsS + pr1 * 256 + ((q0 ^ (pr1 & 15)) << 4));
            h8 a = wreg[t & 1][ks];
            acc0 = __builtin_amdgcn_mfma_f32_32x32x16_f16(a, b0, acc0, 0, 0, 0);
            acc1 = __builtin_amdgcn_mfma_f32_32x32x16_f16(a, b1, acc1, 0, 0, 0);
        }
        // write staged rows after the kh's last kw (all ldsS readers done)
        if (kw == 2 && kh < 2) {
            __syncthreads();                              // readers done
            asm volatile("s_waitcnt vmcnt(0)" ::: "memory");  // staged loads arrived
            #pragma unroll
            for (int it = 0; it < 4; ++it) {
                int ci = it * 512 + tid;
                int r = ci >> 4, q = ci & 15;
                *(uint4*)(ldsS + r * 256 + (((q) ^ (r & 15)) << 4)) = stg[it];
            }
            if (tid < 32) {
                int ci = 2048 + tid;
                int r = ci >> 4, q = ci & 15;
                *(uint4*)(ldsS + r * 256 + (((q) ^ (r & 15)) << 4)) = stg4;
            }
            asm volatile("s_waitcnt lgkmcnt(0)" ::: "memory");
            __syncthreads();                              // new rows visible
        }
    }

    // epilogue: BN2 + fp16 residual (from xh) + ReLU, NCHW store
    #pragma unroll
    for (int j = 0; j < 2; ++j) {
        int p = wp * 64 + j * 32 + lp;
        const unsigned short* xrow = xh + (size_t)((b * 128 + h) * 128 + p) * 128;
        #pragma unroll
        for (int k = 0; k < 4; ++k) {
            int o0 = wq * 32 + k * 8 + hi * 4;
            uint2 rx = *(const uint2*)(xrow + o0);
            __half2 hx0 = *(__half2*)&rx.x;
            __half2 hx1 = *(__half2*)&rx.y;
            float x0 = __low2float(hx0), x1 = __high2float(hx0);
            float x2 = __low2float(hx1), x3 = __high2float(hx1);
            float e0, e1, e2, e3;
            if (j == 0) {
                e0 = acc0[4 * k + 0]; e1 = acc0[4 * k + 1];
                e2 = acc0[4 * k + 2]; e3 = acc0[4 * k + 3];
            } else {
                e0 = acc1[4 * k + 0]; e1 = acc1[4 * k + 1];
                e2 = acc1[4 * k + 2]; e3 = acc1[4 * k + 3];
            }
            size_t idx = ((size_t)(b * C_ + o0) * H_ + h) * W_ + p;
            outp[idx]            = fmaxf(fmaf(e0, inv2[o0 + 0], sh2[o0 + 0]) + x0, 0.f);
            outp[idx + HW]       = fmaxf(fmaf(e1, inv2[o0 + 1], sh2[o0 + 1]) + x1, 0.f);
            outp[idx + 2 * HW]   = fmaxf(fmaf(e2, inv2[o0 + 2], sh2[o0 + 2]) + x2, 0.f);
            outp[idx + 3 * HW]   = fmaxf(fmaf(e3, inv2[o0 + 3], sh2[o0 + 3]) + x3, 0.f);
        }
    }
}

extern "C" void kernel_launch(void* const* d_in, const int* in_sizes, int n_in,
                              void* d_out, int out_size, void* d_ws, size_t ws_size,
                              hipStream_t stream) {
    const float* x   = (const float*)d_in[0];
    const float* off = (const float*)d_in[1];
    const float* w1  = (const float*)d_in[2];
    const float* g1  = (const float*)d_in[3];
    const float* b1  = (const float*)d_in[4];
    const float* m1  = (const float*)d_in[5];
    const float* v1  = (const float*)d_in[6];
    const float* w2  = (const float*)d_in[7];
    const float* g2  = (const float*)d_in[8];
    const float* b2  = (const float*)d_in[9];
    const float* m2  = (const float*)d_in[10];
    const float* v2  = (const float*)d_in[11];
    float* outp = (float*)d_out;

    char* ws = (char*)d_ws;
    unsigned short* w1f = (unsigned short*)(ws);
    unsigned short* w2f = (unsigned short*)(ws + 294912);
    float* inv1 = (float*)(ws + 589824);
    float* sh1  = (float*)(ws + 590336);
    float* inv2 = (float*)(ws + 590848);
    float* sh2  = (float*)(ws + 591360);
    unsigned short* xh  = (unsigned short*)(ws + 591872);
    unsigned short* o1p = (unsigned short*)(ws + 17369088);

    prep_all<<<9474, 256, 0, stream>>>(x, xh, w1, w2, w1f, w2f, o1p,
                                       g1, b1, m1, v1, g2, b2, m2, v2,
                                       inv1, sh1, inv2, sh2);
    gemm1_k<<<1024, 512, 0, stream>>>(xh, off, w1f, inv1, sh1, o1p);
    gemm2_k<<<512, 512, 0, stream>>>(o1p, w2f, xh, inv2, sh2, outp);
}

// Round 19
// 82.711 us; speedup vs baseline: 1.1207x; 1.1207x over previous
//
#include <hip/hip_runtime.h>
#include <hip/hip_fp16.h>
#include <stdint.h>

#define B_ 4
#define C_ 128
#define H_ 128
#define W_ 128
#define HW 16384

typedef _Float16 h8 __attribute__((ext_vector_type(8)));
typedef float f32x16 __attribute__((ext_vector_type(16)));

__device__ __forceinline__ unsigned cvtpk_f16(float lo, float hi) {
    auto r = __builtin_amdgcn_cvt_pkrtz(lo, hi);
    return *(unsigned*)&r;
}

__device__ __forceinline__ unsigned blend_h2(unsigned c0, unsigned c1, unsigned c2, unsigned c3,
                                             __half2 G0, __half2 G1, __half2 G2, __half2 G3) {
    __half2 s = __hmul2(G0, *(__half2*)&c0);
    s = __hfma2(G1, *(__half2*)&c1, s);
    s = __hfma2(G2, *(__half2*)&c2, s);
    s = __hfma2(G3, *(__half2*)&c3, s);
    return *(unsigned*)&s;
}

__device__ __forceinline__ void gll16(const void* g, void* l) {
    __builtin_amdgcn_global_load_lds((const unsigned int*)g, (unsigned int*)l, 16, 0, 0);
}

// producer barrier: drain LDS writes only; global loads stay in flight
#define PBAR() do { \
    asm volatile("s_waitcnt lgkmcnt(0)" ::: "memory"); \
    __builtin_amdgcn_s_barrier(); \
    asm volatile("" ::: "memory"); \
} while (0)
// consumer barrier: no drain
#define CBAR() do { \
    asm volatile("" ::: "memory"); \
    __builtin_amdgcn_s_barrier(); \
    asm volatile("" ::: "memory"); \
} while (0)

// ---------------- fused prep: nhwc transpose + w1/w2 frag pack + border zero + BN fold ----------------
__global__ __launch_bounds__(256) void prep_all(const float* __restrict__ x,
                                                unsigned short* __restrict__ xh,
                                                const float* __restrict__ w1,
                                                const float* __restrict__ w2,
                                                unsigned short* __restrict__ w1f,
                                                unsigned short* __restrict__ w2f,
                                                unsigned short* __restrict__ o1p,
                                                const float* g1, const float* b1, const float* m1, const float* v1,
                                                const float* g2, const float* b2, const float* m2, const float* v2,
                                                float* inv1, float* sh1, float* inv2, float* sh2) {
    __shared__ unsigned short tile[32][36];
    int blk = blockIdx.x;
    int tid = threadIdx.x;
    if (blk >= 1282) {
        int nb = blk - 1282;
        int wt = nb & 3, ct = (nb >> 2) & 3, h = (nb >> 4) & 127, b = nb >> 11;
        int c = tid >> 3, seg = tid & 7;
        const float* srcp = x + ((size_t)((b * 128 + ct * 32 + c) * 128 + h) * 128) + wt * 32 + seg * 4;
        float4 v = *(const float4*)srcp;
        uint2 pk;
        pk.x = cvtpk_f16(v.x, v.y);
        pk.y = cvtpk_f16(v.z, v.w);
        *(uint2*)&tile[c][seg * 4] = pk;
        __syncthreads();
        int w = tid >> 3, s2 = tid & 7;
        unsigned a0 = tile[s2 * 4 + 0][w];
        unsigned a1 = tile[s2 * 4 + 1][w];
        unsigned a2 = tile[s2 * 4 + 2][w];
        unsigned a3 = tile[s2 * 4 + 3][w];
        uint2 o;
        o.x = (a1 << 16) | a0;
        o.y = (a3 << 16) | a2;
        *(uint2*)(xh + ((size_t)((b * 128 + h) * 128 + wt * 32 + w) * 128) + ct * 32 + s2 * 4) = o;
        return;
    }
    if (blk < 1152) {
        int i = blk * 256 + tid;
        const float* src = w1;
        unsigned short* dst = w1f;
        int j = i;
        if (i >= 147456) { j = i - 147456; src = w2; dst = w2f; }
        int o = j / 1152, rem = j % 1152;
        int c = rem / 9, tap = rem % 9;
        _Float16 hv = (_Float16)src[j];
        int s = o >> 5;
        int ks = c >> 4;
        int l = (o & 31) | (((c >> 3) & 1) << 5);
        int jj = c & 7;
        dst[(((tap * 4 + s) * 8 + ks) * 64 + l) * 8 + jj] = *(unsigned short*)&hv;
    } else if (blk < 1281) {
        int i = (blk - 1152) * 256 + tid;
        if (i < 33024) {
            int chunk = i & 15;
            int pos = i >> 4;
            int b = pos / 516;
            int r = pos % 516;
            int row, col;
            if (r < 130)      { row = 0;   col = r; }
            else if (r < 260) { row = 129; col = r - 130; }
            else { int j = r - 260; row = 1 + (j >> 1); col = (j & 1) * 129; }
            uint4 z = {0u, 0u, 0u, 0u};
            *(uint4*)((char*)o1p + (size_t)((b * 130 + row) * 130 + col) * 256 + chunk * 16) = z;
        }
    } else {
        if (tid < 128) {
            float iv = g1[tid] * rsqrtf(v1[tid] + 1e-5f);
            inv1[tid] = iv; sh1[tid] = b1[tid] - m1[tid] * iv;
        } else {
            int u = tid - 128;
            float iv = g2[u] * rsqrtf(v2[u] + 1e-5f);
            inv2[u] = iv; sh2[u] = b2[u] - m2[u] * iv;
        }
    }
}

// ---------------- GEMM1: producer/consumer, fp16, 2-deep producer pipeline, coalesced epilogue ----------------
__global__ __launch_bounds__(512, 4) void gemm1_k(
    const unsigned short* __restrict__ xh,
    const float* __restrict__ off,
    const unsigned short* __restrict__ w1f,
    const float* __restrict__ inv1,
    const float* __restrict__ sh1,
    unsigned short* __restrict__ out1p) {
    __shared__ __align__(16) char ldsv[2][16384];   // [64 p][16 chunks], 4-bit-XOR swz

    int bid = blockIdx.x;
    int swz = ((bid & 7) << 7) | (bid >> 3);
    int half = swz & 1, h = (swz >> 1) & 127, b = swz >> 8;
    int w0 = half * 64;
    int tid = threadIdx.x;
    int bH = b * H_;
    const char* xb8 = (const char*)xh;

    if (tid < 256) {
        // ================= PRODUCER =================
        int prow = tid >> 4;
        int seg = tid & 15;
        int sb = seg * 16;

        float dy[2][4], dx[2][4];
        float g[2][4][4];
        unsigned PX[4][4];
        uint4 buf[4][4];

#define OFFLOAD(TT) do { \
    int dyB_ = ((b * 18 + 2 * (TT)) * H_ + h) * W_ + w0; \
    _Pragma("unroll") \
    for (int c_ = 0; c_ < 4; ++c_) { \
        int p_ = prow + c_ * 16; \
        dy[(TT) & 1][c_] = off[dyB_ + p_]; \
        dx[(TT) & 1][c_] = off[dyB_ + HW + p_]; \
    } \
} while (0)

#define COORD(TT) do { \
    int kh_ = (TT) / 3 - 1, kw_ = (TT) % 3 - 1; \
    _Pragma("unroll") \
    for (int c_ = 0; c_ < 4; ++c_) { \
        int p_ = prow + c_ * 16; \
        float py_ = (float)(h + kh_) + dy[(TT) & 1][c_]; \
        float px_ = (float)(w0 + p_ + kw_) + dx[(TT) & 1][c_]; \
        float y0f_ = floorf(py_), x0f_ = floorf(px_); \
        int y0_ = (int)y0f_, x0_ = (int)x0f_; \
        float wy1_ = py_ - y0f_, wx1_ = px_ - x0f_; \
        float wy0_ = 1.f - wy1_, wx0_ = 1.f - wx1_; \
        int y1_ = y0_ + 1, x1_ = x0_ + 1; \
        g[(TT) & 1][c_][0] = ((unsigned)y0_ < 128u && (unsigned)x0_ < 128u) ? wy0_ * wx0_ : 0.f; \
        g[(TT) & 1][c_][1] = ((unsigned)y0_ < 128u && (unsigned)x1_ < 128u) ? wy0_ * wx1_ : 0.f; \
        g[(TT) & 1][c_][2] = ((unsigned)y1_ < 128u && (unsigned)x0_ < 128u) ? wy1_ * wx0_ : 0.f; \
        g[(TT) & 1][c_][3] = ((unsigned)y1_ < 128u && (unsigned)x1_ < 128u) ? wy1_ * wx1_ : 0.f; \
        int y0c_ = min(max(y0_, 0), 127), y1c_ = min(max(y1_, 0), 127); \
        int x0c_ = min(max(x0_, 0), 127), x1c_ = min(max(x1_, 0), 127); \
        int r0_ = (bH + y0c_) * W_, r1_ = (bH + y1c_) * W_; \
        PX[c_][0] = (unsigned)((r0_ + x0c_) * 256) + sb; \
        PX[c_][1] = (unsigned)((r0_ + x1c_) * 256) + sb; \
        PX[c_][2] = (unsigned)((r1_ + x0c_) * 256) + sb; \
        PX[c_][3] = (unsigned)((r1_ + x1c_) * 256) + sb; \
    } \
} while (0)

#define ISSUE_ALL() do { \
    _Pragma("unroll") \
    for (int c_ = 0; c_ < 4; ++c_) \
        _Pragma("unroll") \
        for (int k_ = 0; k_ < 4; ++k_) buf[c_][k_] = *(const uint4*)(xb8 + PX[c_][k_]); \
} while (0)

#define BLEND_ALL(TT) do { \
    char* vdst_ = &ldsv[(TT) & 1][0]; \
    _Pragma("unroll") \
    for (int c_ = 0; c_ < 4; ++c_) { \
        __half2 G0_ = __float2half2_rn(g[(TT) & 1][c_][0]); \
        __half2 G1_ = __float2half2_rn(g[(TT) & 1][c_][1]); \
        __half2 G2_ = __float2half2_rn(g[(TT) & 1][c_][2]); \
        __half2 G3_ = __float2half2_rn(g[(TT) & 1][c_][3]); \
        uint4 st_; \
        st_.x = blend_h2(buf[c_][0].x, buf[c_][1].x, buf[c_][2].x, buf[c_][3].x, G0_, G1_, G2_, G3_); \
        st_.y = blend_h2(buf[c_][0].y, buf[c_][1].y, buf[c_][2].y, buf[c_][3].y, G0_, G1_, G2_, G3_); \
        st_.z = blend_h2(buf[c_][0].z, buf[c_][1].z, buf[c_][2].z, buf[c_][3].z, G0_, G1_, G2_, G3_); \
        st_.w = blend_h2(buf[c_][0].w, buf[c_][1].w, buf[c_][2].w, buf[c_][3].w, G0_, G1_, G2_, G3_); \
        int row_ = prow + c_ * 16; \
        *(uint4*)(vdst_ + row_ * 256 + ((seg ^ (row_ & 15)) << 4)) = st_; \
    } \
} while (0)

        OFFLOAD(0);
        COORD(0);
        ISSUE_ALL();
        OFFLOAD(1);
        BLEND_ALL(0);
        COORD(1);
        ISSUE_ALL();
        OFFLOAD(2);
        PBAR();

        #pragma unroll
        for (int t = 0; t < 9; ++t) {
            if (t < 8) BLEND_ALL(t + 1);
            if (t < 7) { COORD(t + 2); ISSUE_ALL(); }
            if (t + 3 <= 8) OFFLOAD(t + 3);
            PBAR();
        }
#undef OFFLOAD
#undef COORD
#undef ISSUE_ALL
#undef BLEND_ALL
        CBAR();   // consumers finish writing epilogue tile into ldsv[0]
    } else {
        // ================= CONSUMER =================
        int ctid = tid - 256;
        int lane = ctid & 63, wq = ctid >> 6;
        int lp = lane & 31, hi = lane >> 5;
        int lsw = lp & 15;
        int bRow0 = lp * 256;
        int bRow1 = (32 + lp) * 256;

        f32x16 acc0 = {};
        f32x16 acc1 = {};
        h8 wreg[2][8];

        {
            const unsigned short* wb = w1f + wq * 4096 + lane * 8;
            #pragma unroll
            for (int ks = 0; ks < 8; ++ks) wreg[0][ks] = *(const h8*)(wb + ks * 512);
        }
        CBAR();
        #pragma unroll
        for (int t = 0; t < 9; ++t) {
            if (t < 8) {
                const unsigned short* wb = w1f + ((t + 1) * 4 + wq) * 4096 + lane * 8;
                #pragma unroll
                for (int ks = 0; ks < 8; ++ks) wreg[(t + 1) & 1][ks] = *(const h8*)(wb + ks * 512);
            }
            const char* vcur = &ldsv[t & 1][0];
            #pragma unroll
            for (int ks = 0; ks < 8; ++ks) {
                int q0 = 2 * ks + hi;
                int sl = (q0 ^ lsw) << 4;
                h8 b0 = *(const h8*)(vcur + bRow0 + sl);
                h8 b1 = *(const h8*)(vcur + bRow1 + sl);
                h8 a = wreg[t & 1][ks];
                acc0 = __builtin_amdgcn_mfma_f32_32x32x16_f16(a, b0, acc0, 0, 0, 0);
                acc1 = __builtin_amdgcn_mfma_f32_32x32x16_f16(a, b1, acc1, 0, 0, 0);
            }
            CBAR();
        }

        // epilogue: BN1 + ReLU -> fp16 -> swizzled LDS tile [64 p][128 o]
        char* eb = &ldsv[0][0];
        #pragma unroll
        for (int j = 0; j < 2; ++j) {
            int row = j * 32 + lp;
            #pragma unroll
            for (int k = 0; k < 4; ++k) {
                int o0 = wq * 32 + k * 8 + hi * 4;
                float4 iv = *(const float4*)(inv1 + o0);
                float4 sv = *(const float4*)(sh1 + o0);
                float e0, e1, e2, e3;
                if (j == 0) {
                    e0 = acc0[4 * k + 0]; e1 = acc0[4 * k + 1];
                    e2 = acc0[4 * k + 2]; e3 = acc0[4 * k + 3];
                } else {
                    e0 = acc1[4 * k + 0]; e1 = acc1[4 * k + 1];
                    e2 = acc1[4 * k + 2]; e3 = acc1[4 * k + 3];
                }
                float v0 = fmaxf(fmaf(e0, iv.x, sv.x), 0.f);
                float v1 = fmaxf(fmaf(e1, iv.y, sv.y), 0.f);
                float v2 = fmaxf(fmaf(e2, iv.z, sv.z), 0.f);
                float v3 = fmaxf(fmaf(e3, iv.w, sv.w), 0.f);
                uint2 pk2;
                pk2.x = cvtpk_f16(v0, v1);
                pk2.y = cvtpk_f16(v2, v3);
                int q = wq * 4 + k;
                *(uint2*)(eb + row * 256 + ((q ^ (row & 15)) << 4) + hi * 8) = pk2;
            }
        }
        PBAR();   // drain ds_writes, sync with producers
    }

    // ---- cooperative coalesced halo store (all 512 threads) ----
    {
        const char* eb = &ldsv[0][0];
        char* dstg = (char*)out1p + ((size_t)((b * 130 + h + 1) * 130 + 1 + w0)) * 256;
        #pragma unroll
        for (int it = 0; it < 2; ++it) {
            int ci = it * 512 + tid;
            int row = ci >> 4, q = ci & 15;
            uint4 v = *(const uint4*)(eb + row * 256 + ((q ^ (row & 15)) << 4));
            *(uint4*)(dstg + ci * 16) = v;
        }
    }
}

// ---------------- GEMM2: dense 3x3 conv, weights direct-from-global (frag order) + reg dbuf ----------------
// 512 threads, 8 waves = 4 wq (o-quarter) x 2 wp (p-half); wave owns [32 o x 64 p].
__global__ __launch_bounds__(512, 4) void gemm2_k(
    const unsigned short* __restrict__ out1p,
    const unsigned short* __restrict__ w2f,
    const unsigned short* __restrict__ xh,
    const float* __restrict__ inv2,
    const float* __restrict__ sh2,
    float* __restrict__ outp) {
    __shared__ __align__(16) char ldsS[33280];   // input rows [130][16 chunks] swizzled

    int bid = blockIdx.x;
    int swz = ((bid & 7) << 6) | (bid >> 3);
    int h = swz & 127, b = swz >> 7;
    int tid = threadIdx.x, lane = tid & 63, wv = tid >> 6;
    int wq = wv >> 1, wp = wv & 1;
    int lp = lane & 31, hi = lane >> 5;

    f32x16 acc0 = {};
    f32x16 acc1 = {};
    h8 wreg[2][8];

    // preload tap-0 weight slab
    {
        const unsigned short* wb = w2f + wq * 4096 + lane * 8;
        #pragma unroll
        for (int ks = 0; ks < 8; ++ks) wreg[0][ks] = *(const h8*)(wb + ks * 512);
    }

    #pragma unroll
    for (int t = 0; t < 9; ++t) {
        int kh = t / 3, kw = t % 3;
        if (kw == 0) {
            __syncthreads();   // prev-kh readers done
            const char* srow = (const char*)out1p + (size_t)((b * 130 + h + kh) * 130) * 256;
            #pragma unroll
            for (int it = 0; it < 5; ++it) {
                int ci = it * 512 + tid;
                if (ci < 2080) {
                    int r = ci >> 4, q = ci & 15;
                    gll16(srow + r * 256 + ((q ^ (r & 15)) << 4), ldsS + ci * 16);
                }
            }
            __syncthreads();   // staged (drains vmcnt)
        }
        if (t < 8) {
            const unsigned short* wb = w2f + ((t + 1) * 4 + wq) * 4096 + lane * 8;
            #pragma unroll
            for (int ks = 0; ks < 8; ++ks) wreg[(t + 1) & 1][ks] = *(const h8*)(wb + ks * 512);
        }
        #pragma unroll
        for (int ks = 0; ks < 8; ++ks) {
            int q0 = 2 * ks + hi;
            int pr0 = wp * 64 + lp + kw;
            int pr1 = pr0 + 32;
            h8 b0 = *(const h8*)(ldsS + pr0 * 256 + ((q0 ^ (pr0 & 15)) << 4));
            h8 b1 = *(const h8*)(ldsS + pr1 * 256 + ((q0 ^ (pr1 & 15)) << 4));
            h8 a = wreg[t & 1][ks];
            acc0 = __builtin_amdgcn_mfma_f32_32x32x16_f16(a, b0, acc0, 0, 0, 0);
            acc1 = __builtin_amdgcn_mfma_f32_32x32x16_f16(a, b1, acc1, 0, 0, 0);
        }
    }

    // epilogue: BN2 + fp16 residual (from xh) + ReLU, NCHW store
    #pragma unroll
    for (int j = 0; j < 2; ++j) {
        int p = wp * 64 + j * 32 + lp;
        const unsigned short* xrow = xh + (size_t)((b * 128 + h) * 128 + p) * 128;
        #pragma unroll
        for (int k = 0; k < 4; ++k) {
            int o0 = wq * 32 + k * 8 + hi * 4;
            uint2 rx = *(const uint2*)(xrow + o0);
            __half2 hx0 = *(__half2*)&rx.x;
            __half2 hx1 = *(__half2*)&rx.y;
            float x0 = __low2float(hx0), x1 = __high2float(hx0);
            float x2 = __low2float(hx1), x3 = __high2float(hx1);
            float e0, e1, e2, e3;
            if (j == 0) {
                e0 = acc0[4 * k + 0]; e1 = acc0[4 * k + 1];
                e2 = acc0[4 * k + 2]; e3 = acc0[4 * k + 3];
            } else {
                e0 = acc1[4 * k + 0]; e1 = acc1[4 * k + 1];
                e2 = acc1[4 * k + 2]; e3 = acc1[4 * k + 3];
            }
            size_t idx = ((size_t)(b * C_ + o0) * H_ + h) * W_ + p;
            outp[idx]            = fmaxf(fmaf(e0, inv2[o0 + 0], sh2[o0 + 0]) + x0, 0.f);
            outp[idx + HW]       = fmaxf(fmaf(e1, inv2[o0 + 1], sh2[o0 + 1]) + x1, 0.f);
            outp[idx + 2 * HW]   = fmaxf(fmaf(e2, inv2[o0 + 2], sh2[o0 + 2]) + x2, 0.f);
            outp[idx + 3 * HW]   = fmaxf(fmaf(e3, inv2[o0 + 3], sh2[o0 + 3]) + x3, 0.f);
        }
    }
}

extern "C" void kernel_launch(void* const* d_in, const int* in_sizes, int n_in,
                              void* d_out, int out_size, void* d_ws, size_t ws_size,
                              hipStream_t stream) {
    const float* x   = (const float*)d_in[0];
    const float* off = (const float*)d_in[1];
    const float* w1  = (const float*)d_in[2];
    const float* g1  = (const float*)d_in[3];
    const float* b1  = (const float*)d_in[4];
    const float* m1  = (const float*)d_in[5];
    const float* v1  = (const float*)d_in[6];
    const float* w2  = (const float*)d_in[7];
    const float* g2  = (const float*)d_in[8];
    const float* b2  = (const float*)d_in[9];
    const float* m2  = (const float*)d_in[10];
    const float* v2  = (const float*)d_in[11];
    float* outp = (float*)d_out;

    char* ws = (char*)d_ws;
    unsigned short* w1f = (unsigned short*)(ws);
    unsigned short* w2f = (unsigned short*)(ws + 294912);
    float* inv1 = (float*)(ws + 589824);
    float* sh1  = (float*)(ws + 590336);
    float* inv2 = (float*)(ws + 590848);
    float* sh2  = (float*)(ws + 591360);
    unsigned short* xh  = (unsigned short*)(ws + 591872);
    unsigned short* o1p = (unsigned short*)(ws + 17369088);

    prep_all<<<9474, 256, 0, stream>>>(x, xh, w1, w2, w1f, w2f, o1p,
                                       g1, b1, m1, v1, g2, b2, m2, v2,
                                       inv1, sh1, inv2, sh2);
    gemm1_k<<<1024, 512, 0, stream>>>(xh, off, w1f, inv1, sh1, o1p);
    gemm2_k<<<512, 512, 0, stream>>>(o1p, w2f, xh, inv2, sh2, outp);
}